// Round 6
// baseline (107.057 us; speedup 1.0000x reference)
//
#include <hip/hip_runtime.h>
#include <hip/hip_fp16.h>

// KPConv fused via MFMA for MI355X (gfx950) — round 6.
// B=2, N=32768, K=32 neighbors, S=15 kernel pts, C_in=C_out=128.
//
// vs round 5:
//  - s_fc feature cache REMOVED (features read from L2/L3 in phase 2):
//    LDS 52.7 -> 31.4 KB => 5 blocks/CU by LDS (was 3). Occupancy was the
//    bottleneck (all pipes <26% busy, latency-bound).
//  - full f16 GEMM path: agg accumulated with v_pk_fma_f16 (__hfma2),
//    A-frags stored to LDS as raw half2 (no conversion), W packed f16,
//    mfma_f32_16x16x32_f16. f16 W is MORE precise than round 5's bf16.
//  - g-loop fully unrolled with aggA/aggB ping-pong: group g+1's scattered
//    feature loads issue before group g's MFMAs (latency hidden under MFMA).

typedef __attribute__((ext_vector_type(8))) _Float16 f16x8;
typedef __attribute__((ext_vector_type(4))) float f32x4;

constexpr int KS  = 15;      // kernel points
constexpr int C   = 128;     // C_in = C_out
constexpr int P   = 32;      // points per block
constexpr int NPT = 32768;   // points per batch
constexpr int GS  = 3;       // s per group
constexpr int NG  = 5;       // groups
constexpr int KSG = 12;      // ksteps per group (GS*128/32)
constexpr int NKS = 60;      // total ksteps
constexpr int SLOTS = 16;    // max survivors per point   (P(>16) ~ 1e-14)
constexpr int PAIRS = 88;    // max survivors per block   (mean 46, max~72)

constexpr float R2CUT = 0.0513f;          // beyond: all 15 kw < ~3e-8
constexpr float NEGK  = -801.4972449f;    // -1/(2*0.03^2) * log2(e)

// Pack W[k=1920][o=128] f32 -> Wp[nt 8][gks 60][lane 64][j 8] f16.
// B-frag (16x16x32): lane l holds B[kk = (l>>4)*8 + j][col = l&15].
__global__ void wpack_kernel(const float* __restrict__ W,
                             unsigned short* __restrict__ Wp) {
    const int t   = blockIdx.x * 256 + threadIdx.x;   // 30720 threads
    const int fl  = t & 63;
    const int gks = (t >> 6) % NKS;
    const int nt  = t / (NKS * 64);
    const int o     = nt * 16 + (fl & 15);
    const int kbase = gks * 32 + (fl >> 4) * 8;
    __half v[8] __attribute__((aligned(16)));
    #pragma unroll
    for (int j = 0; j < 8; ++j)
        v[j] = __float2half_rn(W[(size_t)(kbase + j) * C + o]);
    *(uint4*)(Wp + (size_t)t * 8) = *(const uint4*)v;
}

__launch_bounds__(256, 4)
__global__ void kpconv_main(const float* __restrict__ xyz,
                            const float* __restrict__ feat,
                            const int*   __restrict__ nidx,
                            const float* __restrict__ kpts,
                            const unsigned short* __restrict__ Wp,
                            const float* __restrict__ bias,
                            float* __restrict__ out)
{
    __shared__ __align__(16) unsigned short a_lds[2 * KSG * 64 * 8]; // 24576 B
    __shared__ __half2        s_kw2[PAIRS][NG][GS];                  //  5280 B
    __shared__ int            s_gidx[PAIRS];                         //   352 B
    __shared__ unsigned char  s_slotid[P][SLOTS];                    //   512 B
    __shared__ int            s_cnt[P];
    __shared__ int            s_pcnt;
    __shared__ float          s_ctr[P][3];
    __shared__ float          s_kp[KS][3];

    // survivor rel-positions alias a_lds (dead after phase 1b; a_lds first
    // written in the g-loop, after the post-1b barrier)
    float4* const s_rel = reinterpret_cast<float4*>(a_lds);          // 1408 B

    const int tid  = threadIdx.x;
    const int pt0  = blockIdx.x * P;
    const int boff = pt0 & NPT;              // batch row offset (0 or 32768)

    // ---- phase 0 ----
    ((unsigned short*)s_slotid)[tid] = 0xFFFFu;   // sentinel pids
    if (tid < P) s_cnt[tid] = 0;
    if (tid == 255) s_pcnt = 0;
    if (tid < P * 3) ((float*)s_ctr)[tid] = xyz[(size_t)pt0 * 3 + tid];
    if (tid >= 128 && tid < 128 + KS * 3)
        ((float*)s_kp)[tid - 128] = kpts[tid - 128];
    __syncthreads();

    // ---- phase 1: gate 1024 pairs, compact survivors ----
    #pragma unroll
    for (int i = 0; i < 4; ++i) {
        const int q = tid + 256 * i;
        const int p = q >> 5, k = q & 31;
        const int idx = nidx[(pt0 + p) * 32 + k];
        const float rx = xyz[(boff + idx) * 3 + 0] - s_ctr[p][0];
        const float ry = xyz[(boff + idx) * 3 + 1] - s_ctr[p][1];
        const float rz = xyz[(boff + idx) * 3 + 2] - s_ctr[p][2];
        if (rx * rx + ry * ry + rz * rz <= R2CUT) {
            const int slot = atomicAdd(&s_cnt[p], 1);
            if (slot < SLOTS) {
                const int pid = atomicAdd(&s_pcnt, 1);
                if (pid < PAIRS) {
                    s_slotid[p][slot] = (unsigned char)pid;
                    s_gidx[pid] = (boff + idx) << 7;   // feature row offset
                    s_rel[pid] = make_float4(rx, ry, rz, 0.f);
                }
            }
        }
    }
    __syncthreads();

    const int wv   = tid >> 6;
    const int lane = tid & 63;
    const int pcnt = __builtin_amdgcn_readfirstlane(min(s_pcnt, PAIRS));

    // ---- phase 1b: fully parallel kw (one (pid,s) per lane), splat half2 ----
    for (int t = tid; t < pcnt * 16; t += 256) {
        const int pid = t >> 4, s = t & 15;
        if (s < KS) {
            const float4 rel = s_rel[pid];
            const float dx = rel.x - s_kp[s][0];
            const float dy = rel.y - s_kp[s][1];
            const float dz = rel.z - s_kp[s][2];
            const float d2 = dx * dx + dy * dy + dz * dz;
            s_kw2[pid][s / GS][s % GS] =
                __half2half2(__float2half_rn(exp2f(d2 * NEGK)));
        }
    }
    __syncthreads();

    const int pb8 = wv * 8;            // phase-2 point set: 8 per wave
    const int nt0 = wv << 1;           // phase-3: 2 ntiles per wave, both mts
    const int c2  = 2 * lane;          // channel pair

    int cnt_r[8]; int cmax = 0;
    #pragma unroll
    for (int pp = 0; pp < 8; ++pp) {
        int cc = s_cnt[pb8 + pp];
        cc = cc > SLOTS ? SLOTS : cc;
        cnt_r[pp] = __builtin_amdgcn_readfirstlane(cc);
        cmax = max(cmax, cnt_r[pp]);
    }

    f32x4 acc[2][2] = {};              // C/D frags: 2 mtiles x 2 ntiles

    // swizzled-address pieces (same involution as round 5, verified)
    const int q2    = (lane >> 2) & 3;
    const int ksoff = lane >> 4;
    const int dsub  = lane & 3;

    // per-wave B-fragment bases (2 ntiles)
    const unsigned short* wp0 = Wp + ((size_t)(nt0 * NKS) * 64 + lane) * 8;
    const unsigned short* wp1 = wp0 + (size_t)NKS * 64 * 8;

    // ---- phase 2 worker: agg for one s-group, f16 pk-fma ----
    auto phase2 = [&](__half2 (&dst)[8][GS], int g) {
        #pragma unroll
        for (int pp = 0; pp < 8; ++pp)
            #pragma unroll
            for (int sl = 0; sl < GS; ++sl)
                dst[pp][sl] = __float2half2_rn(0.f);
        for (int a = 0; a < cmax; ++a) {
            #pragma unroll
            for (int pp = 0; pp < 8; ++pp) {
                if (a < cnt_r[pp]) {                     // scalar branch
                    const int pid = s_slotid[pb8 + pp][a];
                    if (pid != 0xFF) {
                        const float2 f =
                            *(const float2*)&feat[s_gidx[pid] + c2];
                        const __half2 h = __float22half2_rn(f);
                        #pragma unroll
                        for (int sl = 0; sl < GS; ++sl)
                            dst[pp][sl] =
                                __hfma2(s_kw2[pid][g][sl], h, dst[pp][sl]);
                    }
                }
            }
        }
    };

    // ---- A-frag LDS write: raw half2, swizzled (round-5 involution) ----
    auto write25 = [&](__half2 (&src)[8][GS]) {
        #pragma unroll
        for (int pp = 0; pp < 8; ++pp) {
            const int r   = pb8 + pp;
            const int wmt = r >> 4;
            const int fl  = (r & 15) + 16 * q2;
            #pragma unroll
            for (int sl = 0; sl < GS; ++sl) {
                const int ks = sl * 4 + ksoff;
                unsigned gi = (unsigned)((wmt * KSG + ks) * 64 + fl);
                gi ^= ((gi >> 4) & 3u) << 1;
                gi ^= (gi >> 6) & 1u;
                union { __half2 h; unsigned u; } cv; cv.h = src[pp][sl];
                ((unsigned*)a_lds)[gi * 4 + dsub] = cv.u;
            }
        }
    };

    __half2 aggA[8][GS], aggB[8][GS];
    phase2(aggA, 0);

    #pragma unroll
    for (int g = 0; g < NG; ++g) {
        // ping-pong (g fully unrolled -> static selection, no scratch)
        if (g & 1) write25(aggB); else write25(aggA);
        __syncthreads();

        // issue next group's scattered loads before this group's MFMAs
        if (g + 1 < NG) {
            if (g & 1) phase2(aggA, g + 1); else phase2(aggB, g + 1);
        }

        // ---- phase 3: MFMA, 2mt x 2nt per wave ----
        const unsigned short* w0 = wp0 + (size_t)(g * KSG) * 512;
        const unsigned short* w1 = wp1 + (size_t)(g * KSG) * 512;
        #pragma unroll
        for (int ks = 0; ks < KSG; ++ks) {
            unsigned g0 = (unsigned)(ks * 64 + lane);
            g0 ^= ((g0 >> 4) & 3u) << 1;
            g0 ^= (g0 >> 6) & 1u;
            unsigned g1 = (unsigned)((KSG + ks) * 64 + lane);
            g1 ^= ((g1 >> 4) & 3u) << 1;
            g1 ^= (g1 >> 6) & 1u;
            const f16x8 af0 = *(const f16x8*)&a_lds[g0 * 8];
            const f16x8 af1 = *(const f16x8*)&a_lds[g1 * 8];
            const f16x8 b0  = *(const f16x8*)(w0 + ks * 512);
            const f16x8 b1  = *(const f16x8*)(w1 + ks * 512);
            acc[0][0] = __builtin_amdgcn_mfma_f32_16x16x32_f16(
                            af0, b0, acc[0][0], 0, 0, 0);
            acc[1][0] = __builtin_amdgcn_mfma_f32_16x16x32_f16(
                            af1, b0, acc[1][0], 0, 0, 0);
            acc[0][1] = __builtin_amdgcn_mfma_f32_16x16x32_f16(
                            af0, b1, acc[0][1], 0, 0, 0);
            acc[1][1] = __builtin_amdgcn_mfma_f32_16x16x32_f16(
                            af1, b1, acc[1][1], 0, 0, 0);
        }
        __syncthreads();   // protect a_lds before next group's writes
    }

    // ---- epilogue: C/D layout col=lane&15, row=(lane>>4)*4+reg ----
    const int col = lane & 15;
    const int rg  = lane >> 4;
    #pragma unroll
    for (int nl = 0; nl < 2; ++nl) {
        const int o = (nt0 + nl) * 16 + col;
        const float b = bias[o];
        #pragma unroll
        for (int mt = 0; mt < 2; ++mt) {
            #pragma unroll
            for (int r = 0; r < 4; ++r) {
                const int row = mt * 16 + rg * 4 + r;
                out[((size_t)(pt0 + row) << 7) + o] = acc[mt][nl][r] + b;
            }
        }
    }
}

extern "C" void kernel_launch(void* const* d_in, const int* in_sizes, int n_in,
                              void* d_out, int out_size, void* d_ws, size_t ws_size,
                              hipStream_t stream)
{
    const float* xyz  = (const float*)d_in[0];
    const float* feat = (const float*)d_in[1];
    const int*   nidx = (const int*)  d_in[2];
    const float* kpts = (const float*)d_in[3];
    const float* W    = (const float*)d_in[4];
    const float* bias = (const float*)d_in[5];
    float* out = (float*)d_out;

    unsigned short* Wp = (unsigned short*)d_ws;   // 491,520 B

    wpack_kernel<<<120, 256, 0, stream>>>(W, Wp);

    const int total_pts = in_sizes[0] / 3;        // 65536
    kpconv_main<<<total_pts / P, 256, 0, stream>>>(xyz, feat, nidx, kpts,
                                                   Wp, bias, out);
}

// Round 7
// 74.714 us; speedup vs baseline: 1.4329x; 1.4329x over previous
//
#include <hip/hip_runtime.h>
#include <hip/hip_fp16.h>

// KPConv fused via MFMA for MI355X (gfx950) — round 7.
// B=2, N=32768, K=32 neighbors, S=15 kernel pts, C_in=C_out=128.
//
// vs round 6 (which was latency/barrier-bound, no pipe >20% busy):
//  - SINGLE phase-2 pass: each wave holds agg[4 points][15 s] as channel-
//    packed half2 in 60 VGPRs. Features read once per pair (was 5x);
//    slotid->gidx->feat pointer-chase chains cut 5x.
//  - A staged to LDS in two halves (s0-7 -> MFMA ks0-31; s8-14 -> ks32-59):
//    6 barriers total (was 13), straight-line 64/56-MFMA runs.
//  - 512-thread blocks, 8 waves: phase3 wave = 1 ntile x 2 mtiles, so each
//    B-fragment is read ONCE per block (983 MB L2 total).
//  - swizzle algebra: s*256 / (ks>>1)*128 only touch granule bits >=8, so
//    swizzled LDS addrs = per-lane base + compile-time immediate offset.

typedef __attribute__((ext_vector_type(8))) _Float16 f16x8;
typedef __attribute__((ext_vector_type(4))) float f32x4;

constexpr int KS  = 15;      // kernel points
constexpr int C   = 128;     // C_in = C_out
constexpr int P   = 32;      // points per block
constexpr int NPT = 32768;   // points per batch
constexpr int NKS = 60;      // total ksteps (15*128/32)
constexpr int SLOTS = 16;    // max survivors per point   (P(>16) ~ 1e-14)
constexpr int PAIRS = 88;    // max survivors per block   (mean 46, max~72)

constexpr float R2CUT = 0.0513f;          // beyond: all 15 kw < ~3e-8
constexpr float NEGK  = -801.4972449f;    // -1/(2*0.03^2) * log2(e)

__device__ __forceinline__ unsigned swz(unsigned gi) {
    gi ^= ((gi >> 4) & 3u) << 1;    // bank bits 3-4 ^= q2
    gi ^= (gi >> 6) & 1u;           // bank bit 2  ^= ks parity
    return gi;
}

// Pack W[k=1920][o=128] f32 -> Wp[nt 8][gks 60][lane 64][j 8] f16.
// B-frag (16x16x32): lane l holds B[kk = (l>>4)*8 + j][col = l&15].
__global__ void wpack_kernel(const float* __restrict__ W,
                             unsigned short* __restrict__ Wp) {
    const int t   = blockIdx.x * 256 + threadIdx.x;   // 30720 threads
    const int fl  = t & 63;
    const int gks = (t >> 6) % NKS;
    const int nt  = t / (NKS * 64);
    const int o     = nt * 16 + (fl & 15);
    const int kbase = gks * 32 + (fl >> 4) * 8;
    __half v[8] __attribute__((aligned(16)));
    #pragma unroll
    for (int j = 0; j < 8; ++j)
        v[j] = __float2half_rn(W[(size_t)(kbase + j) * C + o]);
    *(uint4*)(Wp + (size_t)t * 8) = *(const uint4*)v;
}

__launch_bounds__(512, 4)
__global__ void kpconv_main(const float* __restrict__ xyz,
                            const float* __restrict__ feat,
                            const int*   __restrict__ nidx,
                            const float* __restrict__ kpts,
                            const unsigned short* __restrict__ Wp,
                            const float* __restrict__ bias,
                            float* __restrict__ out)
{
    // A half-tile: 2 mt x 32 ks x 64 lanes x 8 halves = 65536 B
    __shared__ __align__(16) unsigned short a_lds[2 * 32 * 64 * 8];
    __shared__ __align__(16) __half2        s_kw2[PAIRS][16];        // 5632 B
    __shared__ int            s_gidx[PAIRS];                         //  352 B
    __shared__ unsigned char  s_slotid[P][SLOTS];                    //  512 B
    __shared__ int            s_cnt[P];
    __shared__ int            s_pcnt;
    __shared__ float          s_ctr[P][3];
    __shared__ float          s_kp[KS][3];

    // survivor rel-positions alias a_lds (dead after phase 1b)
    float4* const s_rel = reinterpret_cast<float4*>(a_lds);          // 1408 B

    const int tid  = threadIdx.x;
    const int pt0  = blockIdx.x * P;
    const int boff = pt0 & NPT;              // batch row offset (0 or 32768)

    // ---- phase 0 ----
    if (tid < 128) ((unsigned*)s_slotid)[tid] = 0xFFFFFFFFu;  // sentinels
    if (tid < P) s_cnt[tid] = 0;
    if (tid == 480) s_pcnt = 0;
    if (tid < P * 3) ((float*)s_ctr)[tid] = xyz[(size_t)pt0 * 3 + tid];
    if (tid >= 128 && tid < 128 + KS * 3)
        ((float*)s_kp)[tid - 128] = kpts[tid - 128];
    __syncthreads();

    // ---- phase 1: gate 1024 pairs, compact survivors ----
    #pragma unroll
    for (int i = 0; i < 2; ++i) {
        const int q = tid + 512 * i;
        const int p = q >> 5, k = q & 31;
        const int idx = nidx[(pt0 + p) * 32 + k];
        const float rx = xyz[(boff + idx) * 3 + 0] - s_ctr[p][0];
        const float ry = xyz[(boff + idx) * 3 + 1] - s_ctr[p][1];
        const float rz = xyz[(boff + idx) * 3 + 2] - s_ctr[p][2];
        if (rx * rx + ry * ry + rz * rz <= R2CUT) {
            const int slot = atomicAdd(&s_cnt[p], 1);
            if (slot < SLOTS) {
                const int pid = atomicAdd(&s_pcnt, 1);
                if (pid < PAIRS) {
                    s_slotid[p][slot] = (unsigned char)pid;
                    s_gidx[pid] = (boff + idx) << 7;   // feature row offset
                    s_rel[pid] = make_float4(rx, ry, rz, 0.f);
                }
            }
        }
    }
    __syncthreads();

    const int wv   = tid >> 6;
    const int lane = tid & 63;
    const int pcnt = __builtin_amdgcn_readfirstlane(min(s_pcnt, PAIRS));

    // ---- phase 1b: fully parallel kw (one (pid,s) per lane), splat half2 ----
    for (int t = tid; t < pcnt * 16; t += 512) {
        const int pid = t >> 4, s = t & 15;
        if (s < KS) {
            const float4 rel = s_rel[pid];
            const float dx = rel.x - s_kp[s][0];
            const float dy = rel.y - s_kp[s][1];
            const float dz = rel.z - s_kp[s][2];
            const float d2 = dx * dx + dy * dy + dz * dz;
            s_kw2[pid][s] = __half2half2(__float2half_rn(exp2f(d2 * NEGK)));
        } else {
            s_kw2[pid][15] = __float2half2_rn(0.f);
        }
    }
    __syncthreads();

    const int pb4 = wv * 4;            // phase-2 point set: 4 per wave
    const int c2  = 2 * lane;          // channel pair

    int cnt_r[4]; int cmax = 0;
    #pragma unroll
    for (int pp = 0; pp < 4; ++pp) {
        int cc = s_cnt[pb4 + pp];
        cc = cc > SLOTS ? SLOTS : cc;
        cnt_r[pp] = __builtin_amdgcn_readfirstlane(cc);
        cmax = max(cmax, cnt_r[pp]);
    }

    // ---- phase 2: SINGLE-pass aggregation, all 15 s in registers ----
    __half2 agg[4][15];
    #pragma unroll
    for (int pp = 0; pp < 4; ++pp)
        #pragma unroll
        for (int s = 0; s < KS; ++s)
            agg[pp][s] = __float2half2_rn(0.f);

    for (int a = 0; a < cmax; ++a) {
        #pragma unroll
        for (int pp = 0; pp < 4; ++pp) {
            if (a < cnt_r[pp]) {                     // wave-uniform branch
                const int pid = s_slotid[pb4 + pp][a];
                if (pid != 0xFF) {
                    const float2 f = *(const float2*)&feat[s_gidx[pid] + c2];
                    const __half2 h = __float22half2_rn(f);
                    union { uint4 v[4]; __half2 h2[16]; } kw;
                    kw.v[0] = *(const uint4*)&s_kw2[pid][0];
                    kw.v[1] = *(const uint4*)&s_kw2[pid][4];
                    kw.v[2] = *(const uint4*)&s_kw2[pid][8];
                    kw.v[3] = *(const uint4*)&s_kw2[pid][12];
                    #pragma unroll
                    for (int s = 0; s < KS; ++s)
                        agg[pp][s] = __hfma2(kw.h2[s], h, agg[pp][s]);
                }
            }
        }
    }

    // ---- swizzled LDS bases (write: word idx; read: byte offset) ----
    const int q2    = (lane >> 2) & 3;
    const int ksoff = lane >> 4;
    const int dsub  = lane & 3;

    int wbaseA[4], wbaseB[4];
    #pragma unroll
    for (int pp = 0; pp < 4; ++pp) {
        const int r   = pb4 + pp;
        const int wmt = r >> 4;
        const int fl  = (r & 15) + 16 * q2;
        wbaseA[pp] = (int)(swz((unsigned)((wmt * 32 + ksoff) * 64 + fl)) * 4
                           + dsub);
        wbaseB[pp] = (int)(swz((unsigned)((wmt * 28 + ksoff) * 64 + fl)) * 4
                           + dsub);
    }
    int rbA[2][2], rbB[2][2];          // [mt][ks parity] byte offsets
    #pragma unroll
    for (int mt = 0; mt < 2; ++mt)
        #pragma unroll
        for (int par = 0; par < 2; ++par) {
            rbA[mt][par] = (int)(swz((unsigned)((mt * 32 + par) * 64 + lane)) * 16);
            rbB[mt][par] = (int)(swz((unsigned)((mt * 28 + par) * 64 + lane)) * 16);
        }

    // per-wave B-fragment base: ntile = wv (each B-frag read once per block)
    const unsigned short* wp = Wp + ((size_t)(wv * NKS) * 64 + lane) * 8;

    f32x4 acc[2] = {};                 // C/D frags: [mt]
    const char* const a_bytes = (const char*)a_lds;

    // ---- phase 2.5a: write s0..7 (ks 0..31) ----
    #pragma unroll
    for (int pp = 0; pp < 4; ++pp)
        #pragma unroll
        for (int s = 0; s < 8; ++s) {
            union { __half2 h; unsigned u; } cv; cv.h = agg[pp][s];
            ((unsigned*)a_lds)[wbaseA[pp] + s * 1024] = cv.u;
        }
    __syncthreads();

    // ---- phase 3a: MFMA ks 0..31 ----
    #pragma unroll
    for (int ks = 0; ks < 32; ++ks) {
        const f16x8 af0 = *(const f16x8*)(a_bytes + rbA[0][ks & 1]
                                          + (ks >> 1) * 2048);
        const f16x8 af1 = *(const f16x8*)(a_bytes + rbA[1][ks & 1]
                                          + (ks >> 1) * 2048);
        const f16x8 b   = *(const f16x8*)(wp + ks * 512);
        acc[0] = __builtin_amdgcn_mfma_f32_16x16x32_f16(af0, b, acc[0], 0, 0, 0);
        acc[1] = __builtin_amdgcn_mfma_f32_16x16x32_f16(af1, b, acc[1], 0, 0, 0);
    }
    __syncthreads();   // all reads of half A done

    // ---- phase 2.5b: write s8..14 (ks 32..59 -> local ks' 0..27) ----
    #pragma unroll
    for (int pp = 0; pp < 4; ++pp)
        #pragma unroll
        for (int s = 8; s < 15; ++s) {
            union { __half2 h; unsigned u; } cv; cv.h = agg[pp][s];
            ((unsigned*)a_lds)[wbaseB[pp] + (s - 8) * 1024] = cv.u;
        }
    __syncthreads();

    // ---- phase 3b: MFMA ks 32..59 ----
    #pragma unroll
    for (int ks = 0; ks < 28; ++ks) {
        const f16x8 af0 = *(const f16x8*)(a_bytes + rbB[0][ks & 1]
                                          + (ks >> 1) * 2048);
        const f16x8 af1 = *(const f16x8*)(a_bytes + rbB[1][ks & 1]
                                          + (ks >> 1) * 2048);
        const f16x8 b   = *(const f16x8*)(wp + (32 + ks) * 512);
        acc[0] = __builtin_amdgcn_mfma_f32_16x16x32_f16(af0, b, acc[0], 0, 0, 0);
        acc[1] = __builtin_amdgcn_mfma_f32_16x16x32_f16(af1, b, acc[1], 0, 0, 0);
    }

    // ---- epilogue: C/D layout col=lane&15, row=(lane>>4)*4+reg ----
    const int col = lane & 15;
    const int rg  = lane >> 4;
    const int o   = wv * 16 + col;
    const float b = bias[o];
    #pragma unroll
    for (int mt = 0; mt < 2; ++mt) {
        #pragma unroll
        for (int r = 0; r < 4; ++r) {
            const int row = mt * 16 + rg * 4 + r;
            out[((size_t)(pt0 + row) << 7) + o] = acc[mt][r] + b;
        }
    }
}

extern "C" void kernel_launch(void* const* d_in, const int* in_sizes, int n_in,
                              void* d_out, int out_size, void* d_ws, size_t ws_size,
                              hipStream_t stream)
{
    const float* xyz  = (const float*)d_in[0];
    const float* feat = (const float*)d_in[1];
    const int*   nidx = (const int*)  d_in[2];
    const float* kpts = (const float*)d_in[3];
    const float* W    = (const float*)d_in[4];
    const float* bias = (const float*)d_in[5];
    float* out = (float*)d_out;

    unsigned short* Wp = (unsigned short*)d_ws;   // 491,520 B

    wpack_kernel<<<120, 256, 0, stream>>>(W, Wp);

    const int total_pts = in_sizes[0] / 3;        // 65536
    kpconv_main<<<total_pts / P, 512, 0, stream>>>(xyz, feat, nidx, kpts,
                                                   Wp, bias, out);
}